// Round 3
// baseline (274.977 us; speedup 1.0000x reference)
//
#include <hip/hip_runtime.h>

// RetrievalLoss: out[i] = -sum_k Q[i,k] * D[i,k]   (N=131072, D=256, fp32)
//
// Round 2 (resubmit; round-2 bench hit GPUAcquisitionTimeout, never ran):
// the round-1 kernel (1 row per wave-iteration, 6 dependent shuffles per
// row) was serialization-bound at 100 us / 2.7 TB/s effective.
// Fix: 8 rows per step (16 float4 loads in flight = 16 KiB/wave MLP) and a
// select-and-fold merge tree that reduces 8 per-lane partials across the
// 64-lane wave in 7 shuffles + 3 butterflies (10 DS ops per 16 KiB instead
// of 48), leaving lane i with row i's sum -> 32 B semi-coalesced store.

constexpr int kN = 131072;
constexpr int kD4 = 64;  // 256 floats = 64 float4 per row

// Merge two cross-lane partial-sum lineages: lanes with (lane&MASK)==0 keep
// the a-lineage, lanes with the bit set keep the b-lineage; both fold in the
// counterpart lane's value of their own lineage.
template <int MASK>
__device__ __forceinline__ float merge2(float a, float b, int lane) {
  float t = (lane & MASK) ? a : b;      // send the counterpart's lineage
  float u = __shfl_xor(t, MASK, 64);    // receive own lineage from lane^MASK
  return ((lane & MASK) ? b : a) + u;
}

__global__ __launch_bounds__(256) void neg_rowdot_kernel(
    const float4* __restrict__ q, const float4* __restrict__ d,
    float* __restrict__ out) {
  const int gwave = (blockIdx.x * blockDim.x + threadIdx.x) >> 6;
  const int lane = threadIdx.x & 63;

  // Each wave owns a contiguous 16-row chunk: rows [gwave*16, gwave*16+16).
  const size_t base = (size_t)gwave * 16;

#pragma unroll
  for (int half = 0; half < 2; ++half) {
    const size_t r0 = base + half * 8;

    // Issue all 16 loads before any compute: 16 KiB in flight per wave.
    float4 qa[8], da[8];
#pragma unroll
    for (int r = 0; r < 8; ++r) {
      qa[r] = q[(r0 + r) * kD4 + lane];
      da[r] = d[(r0 + r) * kD4 + lane];
    }

    float s[8];
#pragma unroll
    for (int r = 0; r < 8; ++r)
      s[r] = qa[r].x * da[r].x + qa[r].y * da[r].y + qa[r].z * da[r].z +
             qa[r].w * da[r].w;

    // Merge tree: after masks 1,2,4 each lane holds the partial sum (over its
    // 8-lane coset) of row (lane & 7); three butterflies finish the 64-lane
    // reduction. 10 shuffles total for 8 rows.
    float m01 = merge2<1>(s[0], s[1], lane);
    float m23 = merge2<1>(s[2], s[3], lane);
    float m45 = merge2<1>(s[4], s[5], lane);
    float m67 = merge2<1>(s[6], s[7], lane);
    float m03 = merge2<2>(m01, m23, lane);
    float m47 = merge2<2>(m45, m67, lane);
    float m07 = merge2<4>(m03, m47, lane);
    m07 += __shfl_xor(m07, 8, 64);
    m07 += __shfl_xor(m07, 16, 64);
    m07 += __shfl_xor(m07, 32, 64);

    if (lane < 8) out[r0 + lane] = -m07;
  }
}

extern "C" void kernel_launch(void* const* d_in, const int* in_sizes, int n_in,
                              void* d_out, int out_size, void* d_ws, size_t ws_size,
                              hipStream_t stream) {
  const float4* q = reinterpret_cast<const float4*>(d_in[0]);
  const float4* d = reinterpret_cast<const float4*>(d_in[1]);
  float* out = reinterpret_cast<float*>(d_out);

  // 2048 blocks x 256 threads = 8192 waves; 16 rows/wave covers N exactly.
  neg_rowdot_kernel<<<2048, 256, 0, stream>>>(q, d, out);
}

// Round 5
// 268.937 us; speedup vs baseline: 1.0225x; 1.0225x over previous
//
#include <hip/hip_runtime.h>

// RetrievalLoss: out[i] = -sum_k Q[i,k] * D[i,k]   (N=131072, D=256, fp32)
//
// Round 4 (resubmit; bench hit GPUAcquisitionTimeout, never ran):
// rounds 1-3 both landed at ~100 us / 2.7 TB/s delivered with
// VGPR_Count <= 32 -- the compiler re-serialized the "batched" loads, so
// each wave held ~1 load in flight against ~2000+ cy congested latency.
// Fix: explicit register double-buffer (4 rows = 8 float4 per buffer),
// next group's loads issued and PINNED via sched_barrier(0) before the
// current group's compute, so the compiler emits counted vmcnt waits and
// 8-16 KiB/wave stays genuinely in flight. ~100 VGPR under
// __launch_bounds__(256,4) -> 16 waves/CU.

constexpr int kD4 = 64;        // 256 floats = 64 float4 per row
constexpr int kG = 4;          // rows per group
constexpr int kGroups = 4;     // groups per wave -> 16 rows/wave

// Merge two cross-lane partial-sum lineages (verified round 3).
template <int MASK>
__device__ __forceinline__ float merge2(float a, float b, int lane) {
  float t = (lane & MASK) ? a : b;    // send the counterpart's lineage
  float u = __shfl_xor(t, MASK, 64);  // receive own lineage from lane^MASK
  return ((lane & MASK) ? b : a) + u;
}

__device__ __forceinline__ float dot4(float4 a, float4 b) {
  return a.x * b.x + a.y * b.y + a.z * b.z + a.w * b.w;
}

__global__ __launch_bounds__(256, 4) void neg_rowdot_kernel(
    const float4* __restrict__ q, const float4* __restrict__ d,
    float* __restrict__ out) {
  const int gwave = (blockIdx.x * blockDim.x + threadIdx.x) >> 6;
  const int lane = threadIdx.x & 63;
  const size_t base = (size_t)gwave * (kG * kGroups);  // 16-row chunk

  float4 qa[kG], da[kG], qb[kG], db[kG];

  // Prologue: load group 0.
#pragma unroll
  for (int r = 0; r < kG; ++r) {
    qa[r] = q[(base + r) * kD4 + lane];
    da[r] = d[(base + r) * kD4 + lane];
  }

#pragma unroll
  for (int g = 0; g < kGroups; ++g) {
    // Issue next group's loads BEFORE computing the current group.
    if (g < kGroups - 1) {
      const size_t nb = base + (size_t)(g + 1) * kG;
#pragma unroll
      for (int r = 0; r < kG; ++r) {
        qb[r] = q[(nb + r) * kD4 + lane];
        db[r] = d[(nb + r) * kD4 + lane];
      }
    }
    // Pin: loads above stay above; compute below stays below. The compiler
    // then waits on the current group with a counted vmcnt (next group's 8
    // loads remain outstanding).
    __builtin_amdgcn_sched_barrier(0);

    float s0 = dot4(qa[0], da[0]);
    float s1 = dot4(qa[1], da[1]);
    float s2 = dot4(qa[2], da[2]);
    float s3 = dot4(qa[3], da[3]);

    // Merge tree: lane ends holding row (lane&3) summed over its 4-lane
    // coset; butterflies 4,8,16,32 finish the 64-lane reduction.
    float m01 = merge2<1>(s0, s1, lane);
    float m23 = merge2<1>(s2, s3, lane);
    float m = merge2<2>(m01, m23, lane);
    m += __shfl_xor(m, 4, 64);
    m += __shfl_xor(m, 8, 64);
    m += __shfl_xor(m, 16, 64);
    m += __shfl_xor(m, 32, 64);

    if (lane < kG) out[base + (size_t)g * kG + lane] = -m;

    // Rotate buffers (renamed away by the register allocator).
    if (g < kGroups - 1) {
#pragma unroll
      for (int r = 0; r < kG; ++r) {
        qa[r] = qb[r];
        da[r] = db[r];
      }
    }
  }
}

extern "C" void kernel_launch(void* const* d_in, const int* in_sizes, int n_in,
                              void* d_out, int out_size, void* d_ws, size_t ws_size,
                              hipStream_t stream) {
  const float4* q = reinterpret_cast<const float4*>(d_in[0]);
  const float4* d = reinterpret_cast<const float4*>(d_in[1]);
  float* out = reinterpret_cast<float*>(d_out);

  // 2048 blocks x 256 threads = 8192 waves x 16 rows = 131072 rows exactly.
  neg_rowdot_kernel<<<2048, 256, 0, stream>>>(q, d, out);
}